// Round 2
// baseline (1171.601 us; speedup 1.0000x reference)
//
#include <hip/hip_runtime.h>
#include <math.h>

// ---------------- problem constants ----------------
constexpr int BATCH  = 2;
constexpr int CDIM   = 96;    // model dim
constexpr int HH     = 56;
constexpr int WW     = 56;
constexpr int LL     = HH * WW;          // 3136
constexpr int DIN    = 192;              // d_inner
constexpr int NK     = 4;                // directions
constexpr int NST    = 16;               // d_state
constexpr int RNK    = 6;                // dt_rank
constexpr int EPROJ  = RNK + 2 * NST;    // 38
constexpr int SCH    = 64;               // steps per scan chunk
constexpr int NCH    = LL / SCH;         // 49 chunks
constexpr int CGRP   = DIN / 16;         // 12 channel-groups of 16
constexpr int NCHAIN = NK * BATCH * CGRP;  // 96 scan chains

// LDS strides (derived for 16B alignment + <=2-way banks)
constexpr int STDU = SCH + 2;   // float2 rows, stride 66
constexpr int STBC = SCH + 6;   // float2 rows, stride 70
constexpr int STY  = SCH + 4;   // float  rows, stride 68

// workspace layout (floats)
constexpr size_t SZ_PX   = (size_t)BATCH * LL * DIN;        // 1,204,224
constexpr size_t OFF_XP  = 0;                               // xp; reused as Pbuf
constexpr size_t OFF_Z   = OFF_XP + SZ_PX;
constexpr size_t OFF_XI  = OFF_Z  + SZ_PX;
constexpr size_t OFF_DR  = OFF_XI + SZ_PX;                  // dr: [kb][L][8]
constexpr size_t SZ_DR   = (size_t)NK * BATCH * LL * 8;
constexpr size_t OFF_B   = OFF_DR + SZ_DR;                  // B: K*B*L*16
constexpr size_t SZ_BC   = (size_t)NK * BATCH * LL * NST;
constexpr size_t OFF_C   = OFF_B + SZ_BC;
constexpr size_t OFF_YD  = OFF_C + SZ_BC;                   // ydir: [k][b][sp][d]
constexpr size_t SZ_YD   = (size_t)NK * BATCH * LL * DIN;   // 4,816,896
constexpr size_t OFF_HE  = OFF_YD + SZ_YD;                  // h_end per chunk
constexpr size_t SZ_HS   = (size_t)NK * BATCH * NCH * DIN * NST;
constexpr size_t OFF_FL  = OFF_HE + SZ_HS;                  // flags: ctr + ready[96]
constexpr size_t SZ_FL   = 256;                             // floats (1KB)
constexpr size_t OFF_WT  = OFF_FL + SZ_FL;                  // Wt: [k][e][d]
constexpr size_t SZ_WT   = (size_t)NK * EPROJ * DIN;        // 29,184

__device__ __forceinline__ float silu(float v) {
    return v / (1.0f + __expf(-v));
}

__device__ __forceinline__ float softplus_f(float x) {
    return (x > 20.0f) ? x : __logf(1.0f + __expf(x));
}

// full 16-lane-row sum via DPP row rotations (VALU only, no LDS pipe).
__device__ __forceinline__ float row_reduce16(float p) {
    p += __int_as_float(__builtin_amdgcn_update_dpp(0, __float_as_int(p), 0x128, 0xf, 0xf, true));
    p += __int_as_float(__builtin_amdgcn_update_dpp(0, __float_as_int(p), 0x124, 0xf, 0xf, true));
    p += __int_as_float(__builtin_amdgcn_update_dpp(0, __float_as_int(p), 0x122, 0xf, 0xf, true));
    p += __int_as_float(__builtin_amdgcn_update_dpp(0, __float_as_int(p), 0x121, 0xf, 0xf, true));
    return p;
}

// direction k, sequence position l -> row-major spatial index
__device__ __forceinline__ int seq_to_lr(int k, int l) {
    int q = l / WW;
    int r = l - q * WW;
    if (k == 0) return l;
    if (k == 1) return q * WW + (WW - 1 - r);
    if (k == 2) return r * WW + q;
    return (WW - 1 - r) * WW + q;
}

// direction k, row-major spatial index s -> sequence position (inverse map)
__device__ __forceinline__ int spatial_to_seq(int k, int s) {
    int h = s / WW;
    int w = s - h * WW;
    if (k == 0) return s;
    if (k == 1) return h * WW + (WW - 1 - w);
    if (k == 2) return w * WW + h;
    return w * WW + (WW - 1 - h);
}

// chunk-summary index: [c][kb][d][n]
__device__ __forceinline__ size_t hs_idx(int c, int kb, int d, int n) {
    return ((size_t)(c * (NK * BATCH) + kb) * DIN + d) * NST + n;
}

// rank-6 delta: vectorized over 4 consecutive d (components of float4)
__device__ __forceinline__ float4 delta4(
        float4 r03, float2 r45, const float4* wr, float4 bb4) {
    float4 raw = bb4;
    raw.x = fmaf(r03.x, wr[0].x, raw.x); raw.y = fmaf(r03.x, wr[0].y, raw.y);
    raw.z = fmaf(r03.x, wr[0].z, raw.z); raw.w = fmaf(r03.x, wr[0].w, raw.w);
    raw.x = fmaf(r03.y, wr[1].x, raw.x); raw.y = fmaf(r03.y, wr[1].y, raw.y);
    raw.z = fmaf(r03.y, wr[1].z, raw.z); raw.w = fmaf(r03.y, wr[1].w, raw.w);
    raw.x = fmaf(r03.z, wr[2].x, raw.x); raw.y = fmaf(r03.z, wr[2].y, raw.y);
    raw.z = fmaf(r03.z, wr[2].z, raw.z); raw.w = fmaf(r03.z, wr[2].w, raw.w);
    raw.x = fmaf(r03.w, wr[3].x, raw.x); raw.y = fmaf(r03.w, wr[3].y, raw.y);
    raw.z = fmaf(r03.w, wr[3].z, raw.z); raw.w = fmaf(r03.w, wr[3].w, raw.w);
    raw.x = fmaf(r45.x, wr[4].x, raw.x); raw.y = fmaf(r45.x, wr[4].y, raw.y);
    raw.z = fmaf(r45.x, wr[4].z, raw.z); raw.w = fmaf(r45.x, wr[4].w, raw.w);
    raw.x = fmaf(r45.y, wr[5].x, raw.x); raw.y = fmaf(r45.y, wr[5].y, raw.y);
    raw.z = fmaf(r45.y, wr[5].z, raw.z); raw.w = fmaf(r45.y, wr[5].w, raw.w);
    raw.x = softplus_f(raw.x); raw.y = softplus_f(raw.y);
    raw.z = softplus_f(raw.z); raw.w = softplus_f(raw.w);
    return raw;
}

// ---------------- kernel 1: in-projection (x^T @ W_in -> xp, z) --------------
// Side job: first threads also transpose W_xproj -> Wt[k][e][d].
constexpr int K1_PIX = 8;
__global__ __launch_bounds__(384) void k_inproj(
        const float* __restrict__ x, const float* __restrict__ W_in,
        const float* __restrict__ W_xproj,
        float* __restrict__ xp, float* __restrict__ z, float* __restrict__ Wt) {
    __shared__ float sxT[CDIM][K1_PIX];   // [c][p], 3 KB
    int gp0 = blockIdx.x * K1_PIX;      // global pixel = b*LL + l
    int t   = threadIdx.x;
    int b   = gp0 / LL;
    int l0  = gp0 - b * LL;
    int gid = blockIdx.x * 384 + t;
    if (gid < NK * DIN * EPROJ) {
        int k = gid / (DIN * EPROJ);
        int r = gid % (DIN * EPROJ);
        int d = r / EPROJ;
        int e = r % EPROJ;
        Wt[((size_t)k * EPROJ + e) * DIN + d] = W_xproj[gid];
    }
    for (int i = t; i < CDIM * K1_PIX; i += 384) {
        int c = i >> 3, p = i & 7;
        sxT[c][p] = x[((size_t)(b * CDIM + c)) * LL + l0 + p];
    }
    __syncthreads();
    int e = t;                          // 0..383 output feature
    float acc[K1_PIX];
#pragma unroll
    for (int p = 0; p < K1_PIX; p++) acc[p] = 0.0f;
    const float4* sx4 = (const float4*)sxT;
#pragma unroll 4
    for (int c = 0; c < CDIM; c++) {
        float w  = W_in[c * (2 * DIN) + e];
        float4 va = sx4[2 * c];
        float4 vb = sx4[2 * c + 1];
        acc[0] = fmaf(va.x, w, acc[0]); acc[1] = fmaf(va.y, w, acc[1]);
        acc[2] = fmaf(va.z, w, acc[2]); acc[3] = fmaf(va.w, w, acc[3]);
        acc[4] = fmaf(vb.x, w, acc[4]); acc[5] = fmaf(vb.y, w, acc[5]);
        acc[6] = fmaf(vb.z, w, acc[6]); acc[7] = fmaf(vb.w, w, acc[7]);
    }
    if (e < DIN) {
#pragma unroll
        for (int p = 0; p < K1_PIX; p++)
            xp[((size_t)(gp0 + p)) * DIN + e] = acc[p];
    } else {
        int e2 = e - DIN;
#pragma unroll
        for (int p = 0; p < K1_PIX; p++)
            z[((size_t)(gp0 + p)) * DIN + e2] = acc[p];
    }
}

// ---------------- kernel 2: depthwise conv 3x3 + bias + SiLU ----------------
__global__ __launch_bounds__(192) void k_conv(
        const float* __restrict__ xp, const float* __restrict__ Wc,
        const float* __restrict__ bc, float* __restrict__ xi) {
    int gp = blockIdx.x;
    int d  = threadIdx.x;
    int b  = gp / LL;
    int l  = gp - b * LL;
    int h  = l / WW;
    int w  = l - h * WW;
    float acc = bc[d];
#pragma unroll
    for (int dy = -1; dy <= 1; dy++) {
        int hh = h + dy;
        if (hh < 0 || hh >= HH) continue;
#pragma unroll
        for (int dx = -1; dx <= 1; dx++) {
            int ww = w + dx;
            if (ww < 0 || ww >= WW) continue;
            acc = fmaf(xp[((size_t)b * LL + hh * WW + ww) * DIN + d],
                       Wc[d * 9 + (dy + 1) * 3 + (dx + 1)], acc);
        }
    }
    xi[(size_t)gp * DIN + d] = silu(acc);
}

// ------- kernel 3: x-proj -> dr (rank-6), B, C ------------------------------
// Weights read straight from L1/L2 (29 KB per direction, shared by all 196
// blocks of that direction; 16-lane broadcast rows). LDS 55 -> 25 KB/block:
// occupancy 2 -> 6 blocks/CU.
constexpr int K3_PIX = 32;
__global__ __launch_bounds__(256) void k_xproj(
        const float* __restrict__ xi, const float* __restrict__ Wt,
        float* __restrict__ drbuf, float* __restrict__ Bbuf,
        float* __restrict__ Cbuf) {
    __shared__ float4 v4[K3_PIX][49];    // 25.1 KB
    int k   = blockIdx.y;
    int gp0 = blockIdx.x * K3_PIX;
    int b   = gp0 / LL;
    int l0  = gp0 - b * LL;
    int t   = threadIdx.x;
    const float4* xin4 = (const float4*)(xi + (size_t)gp0 * DIN);
    for (int i = t; i < K3_PIX * 48; i += 256)
        v4[i / 48][i % 48] = xin4[i];
    const float4* wt4 = (const float4*)(Wt + (size_t)k * EPROJ * DIN);
    __syncthreads();
    int p0 = t & 15;            // pixel within 16-set
    int eg = t >> 4;            // e-group 0..15
    bool has3 = (eg < EPROJ - 32);      // eg < 6
    float acc[2][3] = {{0.f, 0.f, 0.f}, {0.f, 0.f, 0.f}};
#pragma unroll 4
    for (int j = 0; j < 48; j++) {
        float4 w0 = wt4[eg * 48 + j];
        float4 w1 = wt4[(eg + 16) * 48 + j];
        float4 w2 = has3 ? wt4[(eg + 32) * 48 + j] : make_float4(0.f, 0.f, 0.f, 0.f);
#pragma unroll
        for (int q = 0; q < 2; q++) {
            float4 vv = v4[p0 + 16 * q][j];
            acc[q][0] = fmaf(vv.x, w0.x, acc[q][0]); acc[q][0] = fmaf(vv.y, w0.y, acc[q][0]);
            acc[q][0] = fmaf(vv.z, w0.z, acc[q][0]); acc[q][0] = fmaf(vv.w, w0.w, acc[q][0]);
            acc[q][1] = fmaf(vv.x, w1.x, acc[q][1]); acc[q][1] = fmaf(vv.y, w1.y, acc[q][1]);
            acc[q][1] = fmaf(vv.z, w1.z, acc[q][1]); acc[q][1] = fmaf(vv.w, w1.w, acc[q][1]);
            acc[q][2] = fmaf(vv.x, w2.x, acc[q][2]); acc[q][2] = fmaf(vv.y, w2.y, acc[q][2]);
            acc[q][2] = fmaf(vv.z, w2.z, acc[q][2]); acc[q][2] = fmaf(vv.w, w2.w, acc[q][2]);
        }
    }
#pragma unroll
    for (int q = 0; q < 2; q++) {
        int p  = p0 + 16 * q;
        int ls = spatial_to_seq(k, l0 + p);
        size_t kb  = (size_t)(k * BATCH + b);
        size_t b8  = (kb * LL + ls) * 8;
        size_t b16 = (kb * LL + ls) * NST;
        if (eg < RNK) drbuf[b8 + eg] = acc[q][0];
        else          Bbuf[b16 + eg - RNK] = acc[q][0];
        int e1 = eg + 16;
        if (e1 < RNK + NST) Bbuf[b16 + e1 - RNK] = acc[q][1];
        else                Cbuf[b16 + e1 - RNK - NST] = acc[q][1];
        if (has3) Cbuf[b16 + eg + 32 - RNK - NST] = acc[q][2];
    }
}

// -------- kernel 4: fused chunked scan (was scanA + scanB + scanC) ----------
// Decoupled chunk combine with atomic ticket (rocPRIM look-back style):
//   phase 1: stage once (delta4 + xi/dr/B/C -> LDS), local scan from h=0,
//            publish (P, h_end) + release-or a per-chain ready bitmask.
//   combine: poll bitmask until chunks 0..c-1 published, then each thread
//            folds its own (d,n) prefix serially (<=48 coalesced loads).
//   phase 2: re-scan the SAME staged LDS with true h_in; emit y.
// Deadlock-free: publish happens before any wait; a block only waits on
// lower tickets (c fastest-varying), which were acquired earlier in
// scheduling order and publish without waiting.
__global__ __launch_bounds__(256) void k_scan_fused(
        const float* __restrict__ xi, const float* __restrict__ drbuf,
        const float* __restrict__ Bbuf, const float* __restrict__ Cbuf,
        const float* __restrict__ A_logs, const float* __restrict__ W_dt,
        const float* __restrict__ b_dt,
        float* __restrict__ Pbuf, float* __restrict__ hend,
        unsigned int* __restrict__ ctr, unsigned long long* __restrict__ ready,
        float* __restrict__ ydir) {
    __shared__ float2 sDU2[16][STDU];   // [ch][s] {delta, delta*u}
    __shared__ float2 sBC2[16][STBC];   // [n][s]  {B, C}
    __shared__ float  sY[16][STY];      // [ch][s]
    __shared__ unsigned int sVid;
    int t = threadIdx.x;
    if (t == 0) sVid = atomicAdd(ctr, 1u);
    __syncthreads();
    unsigned int vid = sVid;
    int c   = (int)(vid % NCH);
    int blk = (int)(vid / NCH);         // chain id 0..95
    int k   = blk / (BATCH * CGRP);
    int rem = blk % (BATCH * CGRP);
    int b   = rem / CGRP;
    int cg  = rem % CGRP;
    int d0  = cg * 16;
    int lane = t & 63, wave = t >> 6;
    int grp  = lane >> 4, n = lane & 15;
    int ch   = wave * 4 + grp;
    int d    = d0 + ch;
    float A = -__expf(A_logs[((size_t)(k * DIN + d)) * NST + n]);
    size_t kb = (size_t)(k * BATCH + b);
    const float* drp = drbuf + kb * LL * 8;
    const float* bp  = Bbuf  + kb * LL * NST;
    const float* cp  = Cbuf  + kb * LL * NST;
    const float* up  = xi    + (size_t)b * LL * DIN;
    float*       yp  = ydir  + kb * LL * DIN;     // per-direction slice
    // staging identity
    int ss  = t >> 2;            // 0..63
    int cc0 = (t & 3) * 4;       // 0,4,8,12
    float4 wr[RNK];
#pragma unroll
    for (int r = 0; r < RNK; r++)
        wr[r] = *(const float4*)(W_dt + ((size_t)k * RNK + r) * DIN + d0 + cc0);
    float4 bb4 = *(const float4*)(b_dt + k * DIN + d0 + cc0);
    int l0 = c * SCH;
    {
        int l  = l0 + ss;
        int lr = seq_to_lr(k, l);
        float4 r03 = *(const float4*)(drp + (size_t)l * 8);
        float2 r45 = *(const float2*)(drp + (size_t)l * 8 + 4);
        float4 dlt = delta4(r03, r45, wr, bb4);
        float4 u4  = *(const float4*)(up + (size_t)lr * DIN + d0 + cc0);
        float4 B4  = *(const float4*)(bp + (size_t)l * NST + cc0);
        float4 C4  = *(const float4*)(cp + (size_t)l * NST + cc0);
        sDU2[cc0 + 0][ss] = make_float2(dlt.x, dlt.x * u4.x);
        sDU2[cc0 + 1][ss] = make_float2(dlt.y, dlt.y * u4.y);
        sDU2[cc0 + 2][ss] = make_float2(dlt.z, dlt.z * u4.z);
        sDU2[cc0 + 3][ss] = make_float2(dlt.w, dlt.w * u4.w);
        sBC2[cc0 + 0][ss] = make_float2(B4.x, C4.x);
        sBC2[cc0 + 1][ss] = make_float2(B4.y, C4.y);
        sBC2[cc0 + 2][ss] = make_float2(B4.z, C4.z);
        sBC2[cc0 + 3][ss] = make_float2(B4.w, C4.w);
    }
    __syncthreads();
    // ---- phase 1: local scan from h=0, track P = prod(dA) ----
    float h = 0.0f, P = 1.0f;
#pragma unroll 2
    for (int s4 = 0; s4 < SCH; s4 += 4) {
        float4 duA = *(const float4*)&sDU2[ch][s4];
        float4 duB = *(const float4*)&sDU2[ch][s4 + 2];
        float4 bcA = *(const float4*)&sBC2[n][s4];      // {B,C,B,C}
        float4 bcB = *(const float4*)&sBC2[n][s4 + 2];
        float dA;
        dA = __expf(duA.x * A); h = fmaf(dA, h, duA.y * bcA.x); P *= dA;
        dA = __expf(duA.z * A); h = fmaf(dA, h, duA.w * bcA.z); P *= dA;
        dA = __expf(duB.x * A); h = fmaf(dA, h, duB.y * bcB.x); P *= dA;
        dA = __expf(duB.z * A); h = fmaf(dA, h, duB.w * bcB.z); P *= dA;
    }
    // ---- publish chunk summary ----
    {
        size_t idx = hs_idx(c, (int)kb, d, n);
        Pbuf[idx] = P;
        hend[idx] = h;
    }
    __threadfence();            // agent-scope: write back past this XCD's L2
    __syncthreads();            // all 256 threads' summaries are out
    if (t == 0)
        __hip_atomic_fetch_or(&ready[blk], 1ull << c,
                              __ATOMIC_RELEASE, __HIP_MEMORY_SCOPE_AGENT);
    // ---- wait for predecessors + serial combine (this thread's (d,n)) ----
    float hin = 0.0f;
    if (c > 0) {
        if (t == 0) {
            unsigned long long want = (1ull << c) - 1ull;
            while ((__hip_atomic_load(&ready[blk], __ATOMIC_RELAXED,
                                      __HIP_MEMORY_SCOPE_AGENT) & want) != want)
                __builtin_amdgcn_s_sleep(2);
        }
        __syncthreads();
        __threadfence();        // acquire: invalidate stale L1/L2 lines
#pragma unroll 4
        for (int j = 0; j < c; j++) {
            size_t jx = hs_idx(j, (int)kb, d, n);
            hin = fmaf(Pbuf[jx], hin, hend[jx]);
        }
    }
    // ---- phase 2: re-scan same staged LDS with true h_in; emit y ----
    h = hin;
#pragma unroll 2
    for (int s4 = 0; s4 < SCH; s4 += 4) {
        float4 duA = *(const float4*)&sDU2[ch][s4];
        float4 duB = *(const float4*)&sDU2[ch][s4 + 2];
        float4 bcA = *(const float4*)&sBC2[n][s4];
        float4 bcB = *(const float4*)&sBC2[n][s4 + 2];
        float dA, y0, y1, y2, y3;
        dA = __expf(duA.x * A); h = fmaf(dA, h, duA.y * bcA.x); y0 = row_reduce16(h * bcA.y);
        dA = __expf(duA.z * A); h = fmaf(dA, h, duA.w * bcA.z); y1 = row_reduce16(h * bcA.w);
        dA = __expf(duB.x * A); h = fmaf(dA, h, duB.y * bcB.x); y2 = row_reduce16(h * bcB.y);
        dA = __expf(duB.z * A); h = fmaf(dA, h, duB.w * bcB.z); y3 = row_reduce16(h * bcB.w);
        if (n == 0) *(float4*)&sY[ch][s4] = make_float4(y0, y1, y2, y3);
    }
    __syncthreads();
    for (int i = t; i < SCH * 16; i += 256) {
        int s = i >> 4, cc = i & 15;
        int lr = seq_to_lr(k, l0 + s);
        yp[(size_t)lr * DIN + d0 + cc] = sY[cc][s];
    }
}

// ------- kernel 5: gather 4 directions + D*u + gate + out-projection ---------
constexpr int K5_PIX = 8;
__global__ __launch_bounds__(192) void k_out(
        const float* __restrict__ ydir, const float* __restrict__ xi,
        const float* __restrict__ zbuf, const float* __restrict__ Ds,
        const float* __restrict__ W_out, float* __restrict__ out) {
    __shared__ float g[DIN][12];           // [dd][p] padded
    __shared__ float so[CDIM][9];          // padded stores
    int gp0 = blockIdx.x * K5_PIX;
    int b   = gp0 / LL;
    int l0  = gp0 - b * LL;
    int t   = threadIdx.x;
    for (int i = t; i < K5_PIX * DIN; i += 192) {
        int p = i / DIN, dd = i % DIN;
        size_t off = (size_t)(gp0 + p) * DIN + dd;
        float y = ydir[off] + ydir[SZ_PX + off]
                + ydir[2 * SZ_PX + off] + ydir[3 * SZ_PX + off];
        float dsum = Ds[dd] + Ds[DIN + dd] + Ds[2 * DIN + dd] + Ds[3 * DIN + dd];
        y = fmaf(xi[off], dsum, y);
        g[dd][p] = y * silu(zbuf[off]);
    }
    __syncthreads();
    int f    = t % CDIM;
    int half = t / CDIM;
    float acc[4] = {0.f, 0.f, 0.f, 0.f};
#pragma unroll 4
    for (int dd = 0; dd < DIN; dd++) {
        float wv = W_out[dd * CDIM + f];
        float4 gv = *(const float4*)&g[dd][half * 4];
        acc[0] = fmaf(gv.x, wv, acc[0]);
        acc[1] = fmaf(gv.y, wv, acc[1]);
        acc[2] = fmaf(gv.z, wv, acc[2]);
        acc[3] = fmaf(gv.w, wv, acc[3]);
    }
#pragma unroll
    for (int p = 0; p < 4; p++) so[f][half * 4 + p] = acc[p];
    __syncthreads();
    for (int i = t; i < CDIM * K5_PIX; i += 192) {
        int f2 = i / K5_PIX, p2 = i % K5_PIX;
        out[((size_t)(b * CDIM + f2)) * LL + l0 + p2] = so[f2][p2];
    }
}

// ---------------- launch ----------------------------------------------------
extern "C" void kernel_launch(void* const* d_in, const int* in_sizes, int n_in,
                              void* d_out, int out_size, void* d_ws, size_t ws_size,
                              hipStream_t stream) {
    const float* x       = (const float*)d_in[0];
    const float* W_in    = (const float*)d_in[1];
    const float* W_conv  = (const float*)d_in[2];
    const float* b_conv  = (const float*)d_in[3];
    const float* W_xproj = (const float*)d_in[4];
    const float* W_dt    = (const float*)d_in[5];
    const float* b_dt    = (const float*)d_in[6];
    const float* A_logs  = (const float*)d_in[7];
    const float* Ds      = (const float*)d_in[8];
    const float* W_out   = (const float*)d_in[9];
    float* out = (float*)d_out;
    float* ws  = (float*)d_ws;

    float* xp    = ws + OFF_XP;      // dead after k_conv; reused as Pbuf
    float* z     = ws + OFF_Z;
    float* xi    = ws + OFF_XI;
    float* drbuf = ws + OFF_DR;
    float* Bbuf  = ws + OFF_B;
    float* Cbuf  = ws + OFF_C;
    float* ydir  = ws + OFF_YD;
    float* hend  = ws + OFF_HE;
    float* Wt    = ws + OFF_WT;
    float* Pbuf  = xp;
    unsigned int*       ctr   = (unsigned int*)(ws + OFF_FL);
    unsigned long long* ready = (unsigned long long*)(ws + OFF_FL + 2);

    hipMemsetAsync(ws + OFF_FL, 0, SZ_FL * sizeof(float), stream);
    k_inproj<<<(BATCH * LL) / K1_PIX, 384, 0, stream>>>(x, W_in, W_xproj, xp, z, Wt);
    k_conv<<<BATCH * LL, DIN, 0, stream>>>(xp, W_conv, b_conv, xi);
    dim3 g3((BATCH * LL) / K3_PIX, NK);
    k_xproj<<<g3, 256, 0, stream>>>(xi, Wt, drbuf, Bbuf, Cbuf);
    k_scan_fused<<<NCH * NCHAIN, 256, 0, stream>>>(
        xi, drbuf, Bbuf, Cbuf, A_logs, W_dt, b_dt, Pbuf, hend, ctr, ready, ydir);
    k_out<<<(BATCH * LL) / K5_PIX, 192, 0, stream>>>(ydir, xi, z, Ds, W_out, out);
}

// Round 4
// 215.299 us; speedup vs baseline: 5.4417x; 5.4417x over previous
//
#include <hip/hip_runtime.h>
#include <math.h>

// ---------------- problem constants ----------------
constexpr int BATCH  = 2;
constexpr int CDIM   = 96;    // model dim
constexpr int HH     = 56;
constexpr int WW     = 56;
constexpr int LL     = HH * WW;          // 3136
constexpr int DIN    = 192;              // d_inner
constexpr int NK     = 4;                // directions
constexpr int NST    = 16;               // d_state
constexpr int RNK    = 6;                // dt_rank
constexpr int EPROJ  = RNK + 2 * NST;    // 38
constexpr int SCH    = 64;               // steps per scan chunk
constexpr int NCH    = LL / SCH;         // 49 chunks
constexpr int CGRP   = DIN / 16;         // 12 channel-groups of 16

// LDS strides (derived for 16B alignment + <=2-way banks)
constexpr int STDU = SCH + 2;   // float2 rows, stride 66
constexpr int STBC = SCH + 6;   // float2 rows, stride 70
constexpr int STY  = SCH + 4;   // float  rows, stride 68
constexpr int STB1 = SCH + 4;   // float  rows, stride 68

// workspace layout (floats)
constexpr size_t SZ_PX   = (size_t)BATCH * LL * DIN;        // 1,204,224
constexpr size_t OFF_XP  = 0;                               // xp; reused as Pbuf
constexpr size_t OFF_Z   = OFF_XP + SZ_PX;
constexpr size_t OFF_XI  = OFF_Z  + SZ_PX;
constexpr size_t OFF_DR  = OFF_XI + SZ_PX;                  // dr: [kb][L][8]
constexpr size_t SZ_DR   = (size_t)NK * BATCH * LL * 8;
constexpr size_t OFF_B   = OFF_DR + SZ_DR;                  // B: K*B*L*16
constexpr size_t SZ_BC   = (size_t)NK * BATCH * LL * NST;
constexpr size_t OFF_C   = OFF_B + SZ_BC;
constexpr size_t OFF_YD  = OFF_C + SZ_BC;                   // ydir: [k][b][sp][d]
constexpr size_t SZ_YD   = (size_t)NK * BATCH * LL * DIN;   // 4,816,896
constexpr size_t OFF_HE  = OFF_YD + SZ_YD;                  // h_end per chunk
constexpr size_t SZ_HS   = (size_t)NK * BATCH * NCH * DIN * NST;
constexpr size_t OFF_WT  = OFF_HE + SZ_HS;                  // Wt: [k][e][d]
constexpr size_t SZ_WT   = (size_t)NK * EPROJ * DIN;        // 29,184

__device__ __forceinline__ float silu(float v) {
    return v / (1.0f + __expf(-v));
}

__device__ __forceinline__ float softplus_f(float x) {
    return (x > 20.0f) ? x : __logf(1.0f + __expf(x));
}

// full 16-lane-row sum via DPP row rotations (VALU only, no LDS pipe).
__device__ __forceinline__ float row_reduce16(float p) {
    p += __int_as_float(__builtin_amdgcn_update_dpp(0, __float_as_int(p), 0x128, 0xf, 0xf, true));
    p += __int_as_float(__builtin_amdgcn_update_dpp(0, __float_as_int(p), 0x124, 0xf, 0xf, true));
    p += __int_as_float(__builtin_amdgcn_update_dpp(0, __float_as_int(p), 0x122, 0xf, 0xf, true));
    p += __int_as_float(__builtin_amdgcn_update_dpp(0, __float_as_int(p), 0x121, 0xf, 0xf, true));
    return p;
}

// direction k, sequence position l -> row-major spatial index
__device__ __forceinline__ int seq_to_lr(int k, int l) {
    int q = l / WW;
    int r = l - q * WW;
    if (k == 0) return l;
    if (k == 1) return q * WW + (WW - 1 - r);
    if (k == 2) return r * WW + q;
    return (WW - 1 - r) * WW + q;
}

// direction k, row-major spatial index s -> sequence position (inverse map)
__device__ __forceinline__ int spatial_to_seq(int k, int s) {
    int h = s / WW;
    int w = s - h * WW;
    if (k == 0) return s;
    if (k == 1) return h * WW + (WW - 1 - w);
    if (k == 2) return w * WW + h;
    return w * WW + (WW - 1 - h);
}

// chunk-summary index: [c][kb][d][n]
__device__ __forceinline__ size_t hs_idx(int c, int kb, int d, int n) {
    return ((size_t)(c * (NK * BATCH) + kb) * DIN + d) * NST + n;
}

// rank-6 delta: vectorized over 4 consecutive d (components of float4)
__device__ __forceinline__ float4 delta4(
        float4 r03, float2 r45, const float4* wr, float4 bb4) {
    float4 raw = bb4;
    raw.x = fmaf(r03.x, wr[0].x, raw.x); raw.y = fmaf(r03.x, wr[0].y, raw.y);
    raw.z = fmaf(r03.x, wr[0].z, raw.z); raw.w = fmaf(r03.x, wr[0].w, raw.w);
    raw.x = fmaf(r03.y, wr[1].x, raw.x); raw.y = fmaf(r03.y, wr[1].y, raw.y);
    raw.z = fmaf(r03.y, wr[1].z, raw.z); raw.w = fmaf(r03.y, wr[1].w, raw.w);
    raw.x = fmaf(r03.z, wr[2].x, raw.x); raw.y = fmaf(r03.z, wr[2].y, raw.y);
    raw.z = fmaf(r03.z, wr[2].z, raw.z); raw.w = fmaf(r03.z, wr[2].w, raw.w);
    raw.x = fmaf(r03.w, wr[3].x, raw.x); raw.y = fmaf(r03.w, wr[3].y, raw.y);
    raw.z = fmaf(r03.w, wr[3].z, raw.z); raw.w = fmaf(r03.w, wr[3].w, raw.w);
    raw.x = fmaf(r45.x, wr[4].x, raw.x); raw.y = fmaf(r45.x, wr[4].y, raw.y);
    raw.z = fmaf(r45.x, wr[4].z, raw.z); raw.w = fmaf(r45.x, wr[4].w, raw.w);
    raw.x = fmaf(r45.y, wr[5].x, raw.x); raw.y = fmaf(r45.y, wr[5].y, raw.y);
    raw.z = fmaf(r45.y, wr[5].z, raw.z); raw.w = fmaf(r45.y, wr[5].w, raw.w);
    raw.x = softplus_f(raw.x); raw.y = softplus_f(raw.y);
    raw.z = softplus_f(raw.z); raw.w = softplus_f(raw.w);
    return raw;
}

// ---------------- kernel 1: in-projection (x^T @ W_in -> xp, z) --------------
// Side job: first threads also transpose W_xproj -> Wt[k][e][d].
constexpr int K1_PIX = 8;
__global__ __launch_bounds__(384) void k_inproj(
        const float* __restrict__ x, const float* __restrict__ W_in,
        const float* __restrict__ W_xproj,
        float* __restrict__ xp, float* __restrict__ z, float* __restrict__ Wt) {
    __shared__ float sxT[CDIM][K1_PIX];   // [c][p], 3 KB
    int gp0 = blockIdx.x * K1_PIX;      // global pixel = b*LL + l
    int t   = threadIdx.x;
    int b   = gp0 / LL;
    int l0  = gp0 - b * LL;
    int gid = blockIdx.x * 384 + t;
    if (gid < NK * DIN * EPROJ) {
        int k = gid / (DIN * EPROJ);
        int r = gid % (DIN * EPROJ);
        int d = r / EPROJ;
        int e = r % EPROJ;
        Wt[((size_t)k * EPROJ + e) * DIN + d] = W_xproj[gid];
    }
    for (int i = t; i < CDIM * K1_PIX; i += 384) {
        int c = i >> 3, p = i & 7;
        sxT[c][p] = x[((size_t)(b * CDIM + c)) * LL + l0 + p];
    }
    __syncthreads();
    int e = t;                          // 0..383 output feature
    float acc[K1_PIX];
#pragma unroll
    for (int p = 0; p < K1_PIX; p++) acc[p] = 0.0f;
    const float4* sx4 = (const float4*)sxT;
#pragma unroll 4
    for (int c = 0; c < CDIM; c++) {
        float w  = W_in[c * (2 * DIN) + e];
        float4 va = sx4[2 * c];
        float4 vb = sx4[2 * c + 1];
        acc[0] = fmaf(va.x, w, acc[0]); acc[1] = fmaf(va.y, w, acc[1]);
        acc[2] = fmaf(va.z, w, acc[2]); acc[3] = fmaf(va.w, w, acc[3]);
        acc[4] = fmaf(vb.x, w, acc[4]); acc[5] = fmaf(vb.y, w, acc[5]);
        acc[6] = fmaf(vb.z, w, acc[6]); acc[7] = fmaf(vb.w, w, acc[7]);
    }
    if (e < DIN) {
#pragma unroll
        for (int p = 0; p < K1_PIX; p++)
            xp[((size_t)(gp0 + p)) * DIN + e] = acc[p];
    } else {
        int e2 = e - DIN;
#pragma unroll
        for (int p = 0; p < K1_PIX; p++)
            z[((size_t)(gp0 + p)) * DIN + e2] = acc[p];
    }
}

// ---------------- kernel 2: depthwise conv 3x3 + bias + SiLU ----------------
__global__ __launch_bounds__(192) void k_conv(
        const float* __restrict__ xp, const float* __restrict__ Wc,
        const float* __restrict__ bc, float* __restrict__ xi) {
    int gp = blockIdx.x;
    int d  = threadIdx.x;
    int b  = gp / LL;
    int l  = gp - b * LL;
    int h  = l / WW;
    int w  = l - h * WW;
    float acc = bc[d];
#pragma unroll
    for (int dy = -1; dy <= 1; dy++) {
        int hh = h + dy;
        if (hh < 0 || hh >= HH) continue;
#pragma unroll
        for (int dx = -1; dx <= 1; dx++) {
            int ww = w + dx;
            if (ww < 0 || ww >= WW) continue;
            acc = fmaf(xp[((size_t)b * LL + hh * WW + ww) * DIN + d],
                       Wc[d * 9 + (dy + 1) * 3 + (dx + 1)], acc);
        }
    }
    xi[(size_t)gp * DIN + d] = silu(acc);
}

// ------- kernel 3: x-proj -> dr (rank-6), B, C ------------------------------
// Weights read straight from L1/L2 (29 KB per direction, shared by all 196
// blocks of that direction; 16-lane broadcast rows). LDS 55 -> 25 KB/block:
// occupancy 2 -> 6 blocks/CU. (Verified correct in the Round-2 passing run.)
constexpr int K3_PIX = 32;
__global__ __launch_bounds__(256) void k_xproj(
        const float* __restrict__ xi, const float* __restrict__ Wt,
        float* __restrict__ drbuf, float* __restrict__ Bbuf,
        float* __restrict__ Cbuf) {
    __shared__ float4 v4[K3_PIX][49];    // 25.1 KB
    int k   = blockIdx.y;
    int gp0 = blockIdx.x * K3_PIX;
    int b   = gp0 / LL;
    int l0  = gp0 - b * LL;
    int t   = threadIdx.x;
    const float4* xin4 = (const float4*)(xi + (size_t)gp0 * DIN);
    for (int i = t; i < K3_PIX * 48; i += 256)
        v4[i / 48][i % 48] = xin4[i];
    const float4* wt4 = (const float4*)(Wt + (size_t)k * EPROJ * DIN);
    __syncthreads();
    int p0 = t & 15;            // pixel within 16-set
    int eg = t >> 4;            // e-group 0..15
    bool has3 = (eg < EPROJ - 32);      // eg < 6
    float acc[2][3] = {{0.f, 0.f, 0.f}, {0.f, 0.f, 0.f}};
#pragma unroll 4
    for (int j = 0; j < 48; j++) {
        float4 w0 = wt4[eg * 48 + j];
        float4 w1 = wt4[(eg + 16) * 48 + j];
        float4 w2 = has3 ? wt4[(eg + 32) * 48 + j] : make_float4(0.f, 0.f, 0.f, 0.f);
#pragma unroll
        for (int q = 0; q < 2; q++) {
            float4 vv = v4[p0 + 16 * q][j];
            acc[q][0] = fmaf(vv.x, w0.x, acc[q][0]); acc[q][0] = fmaf(vv.y, w0.y, acc[q][0]);
            acc[q][0] = fmaf(vv.z, w0.z, acc[q][0]); acc[q][0] = fmaf(vv.w, w0.w, acc[q][0]);
            acc[q][1] = fmaf(vv.x, w1.x, acc[q][1]); acc[q][1] = fmaf(vv.y, w1.y, acc[q][1]);
            acc[q][1] = fmaf(vv.z, w1.z, acc[q][1]); acc[q][1] = fmaf(vv.w, w1.w, acc[q][1]);
            acc[q][2] = fmaf(vv.x, w2.x, acc[q][2]); acc[q][2] = fmaf(vv.y, w2.y, acc[q][2]);
            acc[q][2] = fmaf(vv.z, w2.z, acc[q][2]); acc[q][2] = fmaf(vv.w, w2.w, acc[q][2]);
        }
    }
#pragma unroll
    for (int q = 0; q < 2; q++) {
        int p  = p0 + 16 * q;
        int ls = spatial_to_seq(k, l0 + p);
        size_t kb  = (size_t)(k * BATCH + b);
        size_t b8  = (kb * LL + ls) * 8;
        size_t b16 = (kb * LL + ls) * NST;
        if (eg < RNK) drbuf[b8 + eg] = acc[q][0];
        else          Bbuf[b16 + eg - RNK] = acc[q][0];
        int e1 = eg + 16;
        if (e1 < RNK + NST) Bbuf[b16 + e1 - RNK] = acc[q][1];
        else                Cbuf[b16 + e1 - RNK - NST] = acc[q][1];
        if (has3) Cbuf[b16 + eg + 32 - RNK - NST] = acc[q][2];
    }
}

// -------- kernel 4a: chunk-local scan -> per-chunk summary (P, h_end) --------
// Staging: thread (s = t>>2, cc0 = (t&3)*4) loads float4s for 4 contiguous cc.
__global__ __launch_bounds__(256) void k_scanA(
        const float* __restrict__ xi, const float* __restrict__ drbuf,
        const float* __restrict__ Bbuf, const float* __restrict__ A_logs,
        const float* __restrict__ W_dt, const float* __restrict__ b_dt,
        float* __restrict__ Pbuf, float* __restrict__ hend) {
    __shared__ float2 sDU2[16][STDU];   // [ch][s] {delta, delta*u}
    __shared__ float  sB1t[16][STB1];   // [n][s]
    int c   = blockIdx.x;
    int blk = blockIdx.y;
    int k   = blk / (BATCH * CGRP);
    int rem = blk % (BATCH * CGRP);
    int b   = rem / CGRP;
    int cg  = rem % CGRP;
    int d0  = cg * 16;
    int t    = threadIdx.x;
    int lane = t & 63, wave = t >> 6;
    int grp  = lane >> 4, n = lane & 15;
    int ch   = wave * 4 + grp;
    int d    = d0 + ch;
    float A = -__expf(A_logs[((size_t)(k * DIN + d)) * NST + n]);
    size_t kb = (size_t)(k * BATCH + b);
    const float* drp = drbuf + kb * LL * 8;
    const float* bp  = Bbuf  + kb * LL * NST;
    const float* up  = xi    + (size_t)b * LL * DIN;
    // staging identity
    int ss  = t >> 2;            // 0..63
    int cc0 = (t & 3) * 4;       // 0,4,8,12
    float4 wr[RNK];
#pragma unroll
    for (int r = 0; r < RNK; r++)
        wr[r] = *(const float4*)(W_dt + ((size_t)k * RNK + r) * DIN + d0 + cc0);
    float4 bb4 = *(const float4*)(b_dt + k * DIN + d0 + cc0);
    int l0 = c * SCH;
    {
        int l  = l0 + ss;
        int lr = seq_to_lr(k, l);
        float4 r03 = *(const float4*)(drp + (size_t)l * 8);
        float2 r45 = *(const float2*)(drp + (size_t)l * 8 + 4);
        float4 dlt = delta4(r03, r45, wr, bb4);
        float4 u4  = *(const float4*)(up + (size_t)lr * DIN + d0 + cc0);
        float4 B4  = *(const float4*)(bp + (size_t)l * NST + cc0);
        sDU2[cc0 + 0][ss] = make_float2(dlt.x, dlt.x * u4.x);
        sDU2[cc0 + 1][ss] = make_float2(dlt.y, dlt.y * u4.y);
        sDU2[cc0 + 2][ss] = make_float2(dlt.z, dlt.z * u4.z);
        sDU2[cc0 + 3][ss] = make_float2(dlt.w, dlt.w * u4.w);
        sB1t[cc0 + 0][ss] = B4.x;
        sB1t[cc0 + 1][ss] = B4.y;
        sB1t[cc0 + 2][ss] = B4.z;
        sB1t[cc0 + 3][ss] = B4.w;
    }
    __syncthreads();
    float h = 0.0f, P = 1.0f;
#pragma unroll 2
    for (int s4 = 0; s4 < SCH; s4 += 4) {
        float4 duA = *(const float4*)&sDU2[ch][s4];
        float4 duB = *(const float4*)&sDU2[ch][s4 + 2];
        float4 bq  = *(const float4*)&sB1t[n][s4];
        float dA;
        dA = __expf(duA.x * A); h = fmaf(dA, h, duA.y * bq.x); P *= dA;
        dA = __expf(duA.z * A); h = fmaf(dA, h, duA.w * bq.y); P *= dA;
        dA = __expf(duB.x * A); h = fmaf(dA, h, duB.y * bq.z); P *= dA;
        dA = __expf(duB.z * A); h = fmaf(dA, h, duB.w * bq.w); P *= dA;
    }
    size_t idx = hs_idx(c, (int)kb, d, n);
    Pbuf[idx] = P;
    hend[idx] = h;
}

// -------- kernel 4b: chunk-local scan with inline prefix fold; emit y --------
// Replaces scanB+scanC: each block folds its own h_in from the (P, h_end)
// summaries written by k_scanA (ordering guaranteed by the kernel boundary —
// no cross-block sync of any kind). Fold order (ascending j) is bit-identical
// to the old scanB. Avg 24 iterations x 2 coalesced 1KB loads/block from L2/L3.
__global__ __launch_bounds__(256) void k_scanC(
        const float* __restrict__ xi, const float* __restrict__ drbuf,
        const float* __restrict__ Bbuf, const float* __restrict__ Cbuf,
        const float* __restrict__ A_logs, const float* __restrict__ W_dt,
        const float* __restrict__ b_dt,
        const float* __restrict__ Pbuf, const float* __restrict__ hend,
        float* __restrict__ ydir) {
    __shared__ float2 sDU2[16][STDU];   // [ch][s] {delta, delta*u}
    __shared__ float2 sBC2[16][STBC];   // [n][s]  {B, C}
    __shared__ float  sY[16][STY];      // [ch][s]
    int c   = blockIdx.x;
    int blk = blockIdx.y;
    int k   = blk / (BATCH * CGRP);
    int rem = blk % (BATCH * CGRP);
    int b   = rem / CGRP;
    int cg  = rem % CGRP;
    int d0  = cg * 16;
    int t    = threadIdx.x;
    int lane = t & 63, wave = t >> 6;
    int grp  = lane >> 4, n = lane & 15;
    int ch   = wave * 4 + grp;
    int d    = d0 + ch;
    float A = -__expf(A_logs[((size_t)(k * DIN + d)) * NST + n]);
    size_t kb = (size_t)(k * BATCH + b);
    const float* drp = drbuf + kb * LL * 8;
    const float* bp  = Bbuf  + kb * LL * NST;
    const float* cp  = Cbuf  + kb * LL * NST;
    const float* up  = xi    + (size_t)b * LL * DIN;
    float*       yp  = ydir  + kb * LL * DIN;     // per-direction slice
    // ---- inline prefix fold: h_in for this (d, n) over chunks 0..c-1 ----
    float hin = 0.0f;
    for (int j = 0; j < c; j++) {
        size_t jx = hs_idx(j, (int)kb, d, n);
        hin = fmaf(Pbuf[jx], hin, hend[jx]);
    }
    // ---- stage chunk data ----
    int ss  = t >> 2;
    int cc0 = (t & 3) * 4;
    float4 wr[RNK];
#pragma unroll
    for (int r = 0; r < RNK; r++)
        wr[r] = *(const float4*)(W_dt + ((size_t)k * RNK + r) * DIN + d0 + cc0);
    float4 bb4 = *(const float4*)(b_dt + k * DIN + d0 + cc0);
    int l0 = c * SCH;
    {
        int l  = l0 + ss;
        int lr = seq_to_lr(k, l);
        float4 r03 = *(const float4*)(drp + (size_t)l * 8);
        float2 r45 = *(const float2*)(drp + (size_t)l * 8 + 4);
        float4 dlt = delta4(r03, r45, wr, bb4);
        float4 u4  = *(const float4*)(up + (size_t)lr * DIN + d0 + cc0);
        float4 B4  = *(const float4*)(bp + (size_t)l * NST + cc0);
        float4 C4  = *(const float4*)(cp + (size_t)l * NST + cc0);
        sDU2[cc0 + 0][ss] = make_float2(dlt.x, dlt.x * u4.x);
        sDU2[cc0 + 1][ss] = make_float2(dlt.y, dlt.y * u4.y);
        sDU2[cc0 + 2][ss] = make_float2(dlt.z, dlt.z * u4.z);
        sDU2[cc0 + 3][ss] = make_float2(dlt.w, dlt.w * u4.w);
        sBC2[cc0 + 0][ss] = make_float2(B4.x, C4.x);
        sBC2[cc0 + 1][ss] = make_float2(B4.y, C4.y);
        sBC2[cc0 + 2][ss] = make_float2(B4.z, C4.z);
        sBC2[cc0 + 3][ss] = make_float2(B4.w, C4.w);
    }
    __syncthreads();
    float h = hin;
#pragma unroll 2
    for (int s4 = 0; s4 < SCH; s4 += 4) {
        float4 duA = *(const float4*)&sDU2[ch][s4];
        float4 duB = *(const float4*)&sDU2[ch][s4 + 2];
        float4 bcA = *(const float4*)&sBC2[n][s4];
        float4 bcB = *(const float4*)&sBC2[n][s4 + 2];
        float dA, y0, y1, y2, y3;
        dA = __expf(duA.x * A); h = fmaf(dA, h, duA.y * bcA.x); y0 = row_reduce16(h * bcA.y);
        dA = __expf(duA.z * A); h = fmaf(dA, h, duA.w * bcA.z); y1 = row_reduce16(h * bcA.w);
        dA = __expf(duB.x * A); h = fmaf(dA, h, duB.y * bcB.x); y2 = row_reduce16(h * bcB.y);
        dA = __expf(duB.z * A); h = fmaf(dA, h, duB.w * bcB.z); y3 = row_reduce16(h * bcB.w);
        if (n == 0) *(float4*)&sY[ch][s4] = make_float4(y0, y1, y2, y3);
    }
    __syncthreads();
    for (int i = t; i < SCH * 16; i += 256) {
        int s = i >> 4, cc = i & 15;
        int lr = seq_to_lr(k, l0 + s);
        yp[(size_t)lr * DIN + d0 + cc] = sY[cc][s];
    }
}

// ------- kernel 5: gather 4 directions + D*u + gate + out-projection ---------
constexpr int K5_PIX = 8;
__global__ __launch_bounds__(192) void k_out(
        const float* __restrict__ ydir, const float* __restrict__ xi,
        const float* __restrict__ zbuf, const float* __restrict__ Ds,
        const float* __restrict__ W_out, float* __restrict__ out) {
    __shared__ float g[DIN][12];           // [dd][p] padded
    __shared__ float so[CDIM][9];          // padded stores
    int gp0 = blockIdx.x * K5_PIX;
    int b   = gp0 / LL;
    int l0  = gp0 - b * LL;
    int t   = threadIdx.x;
    for (int i = t; i < K5_PIX * DIN; i += 192) {
        int p = i / DIN, dd = i % DIN;
        size_t off = (size_t)(gp0 + p) * DIN + dd;
        float y = ydir[off] + ydir[SZ_PX + off]
                + ydir[2 * SZ_PX + off] + ydir[3 * SZ_PX + off];
        float dsum = Ds[dd] + Ds[DIN + dd] + Ds[2 * DIN + dd] + Ds[3 * DIN + dd];
        y = fmaf(xi[off], dsum, y);
        g[dd][p] = y * silu(zbuf[off]);
    }
    __syncthreads();
    int f    = t % CDIM;
    int half = t / CDIM;
    float acc[4] = {0.f, 0.f, 0.f, 0.f};
#pragma unroll 4
    for (int dd = 0; dd < DIN; dd++) {
        float wv = W_out[dd * CDIM + f];
        float4 gv = *(const float4*)&g[dd][half * 4];
        acc[0] = fmaf(gv.x, wv, acc[0]);
        acc[1] = fmaf(gv.y, wv, acc[1]);
        acc[2] = fmaf(gv.z, wv, acc[2]);
        acc[3] = fmaf(gv.w, wv, acc[3]);
    }
#pragma unroll
    for (int p = 0; p < 4; p++) so[f][half * 4 + p] = acc[p];
    __syncthreads();
    for (int i = t; i < CDIM * K5_PIX; i += 192) {
        int f2 = i / K5_PIX, p2 = i % K5_PIX;
        out[((size_t)(b * CDIM + f2)) * LL + l0 + p2] = so[f2][p2];
    }
}

// ---------------- launch ----------------------------------------------------
extern "C" void kernel_launch(void* const* d_in, const int* in_sizes, int n_in,
                              void* d_out, int out_size, void* d_ws, size_t ws_size,
                              hipStream_t stream) {
    const float* x       = (const float*)d_in[0];
    const float* W_in    = (const float*)d_in[1];
    const float* W_conv  = (const float*)d_in[2];
    const float* b_conv  = (const float*)d_in[3];
    const float* W_xproj = (const float*)d_in[4];
    const float* W_dt    = (const float*)d_in[5];
    const float* b_dt    = (const float*)d_in[6];
    const float* A_logs  = (const float*)d_in[7];
    const float* Ds      = (const float*)d_in[8];
    const float* W_out   = (const float*)d_in[9];
    float* out = (float*)d_out;
    float* ws  = (float*)d_ws;

    float* xp    = ws + OFF_XP;      // dead after k_conv; reused as Pbuf
    float* z     = ws + OFF_Z;
    float* xi    = ws + OFF_XI;
    float* drbuf = ws + OFF_DR;
    float* Bbuf  = ws + OFF_B;
    float* Cbuf  = ws + OFF_C;
    float* ydir  = ws + OFF_YD;
    float* hend  = ws + OFF_HE;
    float* Wt    = ws + OFF_WT;
    float* Pbuf  = xp;

    k_inproj<<<(BATCH * LL) / K1_PIX, 384, 0, stream>>>(x, W_in, W_xproj, xp, z, Wt);
    k_conv<<<BATCH * LL, DIN, 0, stream>>>(xp, W_conv, b_conv, xi);
    dim3 g3((BATCH * LL) / K3_PIX, NK);
    k_xproj<<<g3, 256, 0, stream>>>(xi, Wt, drbuf, Bbuf, Cbuf);
    dim3 gs(NCH, NK * BATCH * CGRP);
    k_scanA<<<gs, 256, 0, stream>>>(xi, drbuf, Bbuf, A_logs, W_dt, b_dt, Pbuf, hend);
    k_scanC<<<gs, 256, 0, stream>>>(xi, drbuf, Bbuf, Cbuf, A_logs, W_dt, b_dt, Pbuf, hend, ydir);
    k_out<<<(BATCH * LL) / K5_PIX, 192, 0, stream>>>(ydir, xi, z, Ds, W_out, out);
}

// Round 5
// 197.292 us; speedup vs baseline: 5.9384x; 1.0913x over previous
//
#include <hip/hip_runtime.h>
#include <math.h>

// ---------------- problem constants ----------------
constexpr int BATCH  = 2;
constexpr int CDIM   = 96;    // model dim
constexpr int HH     = 56;
constexpr int WW     = 56;
constexpr int LL     = HH * WW;          // 3136
constexpr int DIN    = 192;              // d_inner
constexpr int NK     = 4;                // directions
constexpr int NST    = 16;               // d_state
constexpr int RNK    = 6;                // dt_rank
constexpr int EPROJ  = RNK + 2 * NST;    // 38
constexpr int SCH    = 64;               // steps per scan chunk
constexpr int NCH    = LL / SCH;         // 49 chunks
constexpr int CGRP   = DIN / 16;         // 12 channel-groups of 16

// LDS strides (derived for 16B alignment + <=2-way banks)
constexpr int STDU = SCH + 2;   // float2 rows, stride 66
constexpr int STBC = SCH + 6;   // float2 rows, stride 70
constexpr int STY  = SCH + 4;   // float  rows, stride 68
constexpr int STB1 = SCH + 4;   // float  rows, stride 68

// workspace layout (floats)
constexpr size_t SZ_PX   = (size_t)BATCH * LL * DIN;        // 1,204,224
constexpr size_t OFF_XP  = 0;
constexpr size_t OFF_Z   = OFF_XP + SZ_PX;
constexpr size_t OFF_XI  = OFF_Z  + SZ_PX;
constexpr size_t OFF_DR  = OFF_XI + SZ_PX;                  // dr: [kb][L][8]
constexpr size_t SZ_DR   = (size_t)NK * BATCH * LL * 8;
constexpr size_t OFF_B   = OFF_DR + SZ_DR;                  // B: K*B*L*16
constexpr size_t SZ_BC   = (size_t)NK * BATCH * LL * NST;
constexpr size_t OFF_C   = OFF_B + SZ_BC;
constexpr size_t OFF_YD  = OFF_C + SZ_BC;                   // ydir: [k][b][sp][d]
constexpr size_t SZ_YD   = (size_t)NK * BATCH * LL * DIN;   // 4,816,896
constexpr size_t OFF_HE  = OFF_YD + SZ_YD;                  // (P, h_end) float2 per chunk
constexpr size_t SZ_HS   = (size_t)NK * BATCH * NCH * DIN * NST;
constexpr size_t OFF_WT  = OFF_HE + 2 * SZ_HS;              // Wt: [k][e][d]
constexpr size_t SZ_WT   = (size_t)NK * EPROJ * DIN;        // 29,184

__device__ __forceinline__ float silu(float v) {
    return v / (1.0f + __expf(-v));
}

__device__ __forceinline__ float softplus_f(float x) {
    return (x > 20.0f) ? x : __logf(1.0f + __expf(x));
}

// full 16-lane-row sum via DPP row rotations (VALU only, no LDS pipe).
__device__ __forceinline__ float row_reduce16(float p) {
    p += __int_as_float(__builtin_amdgcn_update_dpp(0, __float_as_int(p), 0x128, 0xf, 0xf, true));
    p += __int_as_float(__builtin_amdgcn_update_dpp(0, __float_as_int(p), 0x124, 0xf, 0xf, true));
    p += __int_as_float(__builtin_amdgcn_update_dpp(0, __float_as_int(p), 0x122, 0xf, 0xf, true));
    p += __int_as_float(__builtin_amdgcn_update_dpp(0, __float_as_int(p), 0x121, 0xf, 0xf, true));
    return p;
}

// direction k, sequence position l -> row-major spatial index
__device__ __forceinline__ int seq_to_lr(int k, int l) {
    int q = l / WW;
    int r = l - q * WW;
    if (k == 0) return l;
    if (k == 1) return q * WW + (WW - 1 - r);
    if (k == 2) return r * WW + q;
    return (WW - 1 - r) * WW + q;
}

// direction k, row-major spatial index s -> sequence position (inverse map)
__device__ __forceinline__ int spatial_to_seq(int k, int s) {
    int h = s / WW;
    int w = s - h * WW;
    if (k == 0) return s;
    if (k == 1) return h * WW + (WW - 1 - w);
    if (k == 2) return w * WW + h;
    return w * WW + (WW - 1 - h);
}

// chunk-summary index: [c][kb][d][n]
__device__ __forceinline__ size_t hs_idx(int c, int kb, int d, int n) {
    return ((size_t)(c * (NK * BATCH) + kb) * DIN + d) * NST + n;
}

// rank-6 delta: vectorized over 4 consecutive d (components of float4)
__device__ __forceinline__ float4 delta4(
        float4 r03, float2 r45, const float4* wr, float4 bb4) {
    float4 raw = bb4;
    raw.x = fmaf(r03.x, wr[0].x, raw.x); raw.y = fmaf(r03.x, wr[0].y, raw.y);
    raw.z = fmaf(r03.x, wr[0].z, raw.z); raw.w = fmaf(r03.x, wr[0].w, raw.w);
    raw.x = fmaf(r03.y, wr[1].x, raw.x); raw.y = fmaf(r03.y, wr[1].y, raw.y);
    raw.z = fmaf(r03.y, wr[1].z, raw.z); raw.w = fmaf(r03.y, wr[1].w, raw.w);
    raw.x = fmaf(r03.z, wr[2].x, raw.x); raw.y = fmaf(r03.z, wr[2].y, raw.y);
    raw.z = fmaf(r03.z, wr[2].z, raw.z); raw.w = fmaf(r03.z, wr[2].w, raw.w);
    raw.x = fmaf(r03.w, wr[3].x, raw.x); raw.y = fmaf(r03.w, wr[3].y, raw.y);
    raw.z = fmaf(r03.w, wr[3].z, raw.z); raw.w = fmaf(r03.w, wr[3].w, raw.w);
    raw.x = fmaf(r45.x, wr[4].x, raw.x); raw.y = fmaf(r45.x, wr[4].y, raw.y);
    raw.z = fmaf(r45.x, wr[4].z, raw.z); raw.w = fmaf(r45.x, wr[4].w, raw.w);
    raw.x = fmaf(r45.y, wr[5].x, raw.x); raw.y = fmaf(r45.y, wr[5].y, raw.y);
    raw.z = fmaf(r45.y, wr[5].z, raw.z); raw.w = fmaf(r45.y, wr[5].w, raw.w);
    raw.x = softplus_f(raw.x); raw.y = softplus_f(raw.y);
    raw.z = softplus_f(raw.z); raw.w = softplus_f(raw.w);
    return raw;
}

// ---------------- kernel 1: in-projection (x^T @ W_in -> xp, z) --------------
// Side job: first threads also transpose W_xproj -> Wt[k][e][d].
constexpr int K1_PIX = 8;
__global__ __launch_bounds__(384) void k_inproj(
        const float* __restrict__ x, const float* __restrict__ W_in,
        const float* __restrict__ W_xproj,
        float* __restrict__ xp, float* __restrict__ z, float* __restrict__ Wt) {
    __shared__ float sxT[CDIM][K1_PIX];   // [c][p], 3 KB
    int gp0 = blockIdx.x * K1_PIX;      // global pixel = b*LL + l
    int t   = threadIdx.x;
    int b   = gp0 / LL;
    int l0  = gp0 - b * LL;
    int gid = blockIdx.x * 384 + t;
    if (gid < NK * DIN * EPROJ) {
        int k = gid / (DIN * EPROJ);
        int r = gid % (DIN * EPROJ);
        int d = r / EPROJ;
        int e = r % EPROJ;
        Wt[((size_t)k * EPROJ + e) * DIN + d] = W_xproj[gid];
    }
    for (int i = t; i < CDIM * K1_PIX; i += 384) {
        int c = i >> 3, p = i & 7;
        sxT[c][p] = x[((size_t)(b * CDIM + c)) * LL + l0 + p];
    }
    __syncthreads();
    int e = t;                          // 0..383 output feature
    float acc[K1_PIX];
#pragma unroll
    for (int p = 0; p < K1_PIX; p++) acc[p] = 0.0f;
    const float4* sx4 = (const float4*)sxT;
#pragma unroll 4
    for (int c = 0; c < CDIM; c++) {
        float w  = W_in[c * (2 * DIN) + e];
        float4 va = sx4[2 * c];
        float4 vb = sx4[2 * c + 1];
        acc[0] = fmaf(va.x, w, acc[0]); acc[1] = fmaf(va.y, w, acc[1]);
        acc[2] = fmaf(va.z, w, acc[2]); acc[3] = fmaf(va.w, w, acc[3]);
        acc[4] = fmaf(vb.x, w, acc[4]); acc[5] = fmaf(vb.y, w, acc[5]);
        acc[6] = fmaf(vb.z, w, acc[6]); acc[7] = fmaf(vb.w, w, acc[7]);
    }
    if (e < DIN) {
#pragma unroll
        for (int p = 0; p < K1_PIX; p++)
            xp[((size_t)(gp0 + p)) * DIN + e] = acc[p];
    } else {
        int e2 = e - DIN;
#pragma unroll
        for (int p = 0; p < K1_PIX; p++)
            z[((size_t)(gp0 + p)) * DIN + e2] = acc[p];
    }
}

// ---------------- kernel 2: depthwise conv 3x3 + bias + SiLU ----------------
// Vectorized float4 over channels (G13): 4 pixels/block, 48 ch-groups,
// weights staged transposed in LDS. 9 float4 loads per thread vs 36 scalar.
constexpr int KC_PIX = 4;
__global__ __launch_bounds__(192) void k_conv(
        const float* __restrict__ xp, const float* __restrict__ Wc,
        const float* __restrict__ bc, float* __restrict__ xi) {
    __shared__ float sW[9][DIN];          // 6.9 KB, transposed weights
    int t = threadIdx.x;
    for (int i = t; i < DIN * 9; i += 192) {
        int d = i / 9, tap = i % 9;
        sW[tap][d] = Wc[i];
    }
    __syncthreads();
    int p   = t / 48;            // pixel within block 0..3
    int cg4 = (t % 48) * 4;      // channel quad
    int gp  = blockIdx.x * KC_PIX + p;
    int b   = gp / LL;
    int l   = gp - b * LL;
    int h   = l / WW;
    int w   = l - h * WW;
    float4 acc = *(const float4*)&bc[cg4];
#pragma unroll
    for (int dy = -1; dy <= 1; dy++) {
        int hh = h + dy;
        if (hh < 0 || hh >= HH) continue;
#pragma unroll
        for (int dx = -1; dx <= 1; dx++) {
            int ww = w + dx;
            if (ww < 0 || ww >= WW) continue;
            float4 xv = *(const float4*)&xp[((size_t)b * LL + hh * WW + ww) * DIN + cg4];
            float4 wv = *(const float4*)&sW[(dy + 1) * 3 + (dx + 1)][cg4];
            acc.x = fmaf(xv.x, wv.x, acc.x);
            acc.y = fmaf(xv.y, wv.y, acc.y);
            acc.z = fmaf(xv.z, wv.z, acc.z);
            acc.w = fmaf(xv.w, wv.w, acc.w);
        }
    }
    float4 o;
    o.x = silu(acc.x); o.y = silu(acc.y); o.z = silu(acc.z); o.w = silu(acc.w);
    *(float4*)&xi[(size_t)gp * DIN + cg4] = o;
}

// ------- kernel 3: x-proj -> dr (rank-6), B, C ------------------------------
// Weights read straight from L1/L2 (29 KB per direction, shared by all 196
// blocks of that direction; 16-lane broadcast rows).
constexpr int K3_PIX = 32;
__global__ __launch_bounds__(256) void k_xproj(
        const float* __restrict__ xi, const float* __restrict__ Wt,
        float* __restrict__ drbuf, float* __restrict__ Bbuf,
        float* __restrict__ Cbuf) {
    __shared__ float4 v4[K3_PIX][49];    // 25.1 KB
    int k   = blockIdx.y;
    int gp0 = blockIdx.x * K3_PIX;
    int b   = gp0 / LL;
    int l0  = gp0 - b * LL;
    int t   = threadIdx.x;
    const float4* xin4 = (const float4*)(xi + (size_t)gp0 * DIN);
    for (int i = t; i < K3_PIX * 48; i += 256)
        v4[i / 48][i % 48] = xin4[i];
    const float4* wt4 = (const float4*)(Wt + (size_t)k * EPROJ * DIN);
    __syncthreads();
    int p0 = t & 15;            // pixel within 16-set
    int eg = t >> 4;            // e-group 0..15
    bool has3 = (eg < EPROJ - 32);      // eg < 6
    float acc[2][3] = {{0.f, 0.f, 0.f}, {0.f, 0.f, 0.f}};
#pragma unroll 4
    for (int j = 0; j < 48; j++) {
        float4 w0 = wt4[eg * 48 + j];
        float4 w1 = wt4[(eg + 16) * 48 + j];
        float4 w2 = has3 ? wt4[(eg + 32) * 48 + j] : make_float4(0.f, 0.f, 0.f, 0.f);
#pragma unroll
        for (int q = 0; q < 2; q++) {
            float4 vv = v4[p0 + 16 * q][j];
            acc[q][0] = fmaf(vv.x, w0.x, acc[q][0]); acc[q][0] = fmaf(vv.y, w0.y, acc[q][0]);
            acc[q][0] = fmaf(vv.z, w0.z, acc[q][0]); acc[q][0] = fmaf(vv.w, w0.w, acc[q][0]);
            acc[q][1] = fmaf(vv.x, w1.x, acc[q][1]); acc[q][1] = fmaf(vv.y, w1.y, acc[q][1]);
            acc[q][1] = fmaf(vv.z, w1.z, acc[q][1]); acc[q][1] = fmaf(vv.w, w1.w, acc[q][1]);
            acc[q][2] = fmaf(vv.x, w2.x, acc[q][2]); acc[q][2] = fmaf(vv.y, w2.y, acc[q][2]);
            acc[q][2] = fmaf(vv.z, w2.z, acc[q][2]); acc[q][2] = fmaf(vv.w, w2.w, acc[q][2]);
        }
    }
#pragma unroll
    for (int q = 0; q < 2; q++) {
        int p  = p0 + 16 * q;
        int ls = spatial_to_seq(k, l0 + p);
        size_t kb  = (size_t)(k * BATCH + b);
        size_t b8  = (kb * LL + ls) * 8;
        size_t b16 = (kb * LL + ls) * NST;
        if (eg < RNK) drbuf[b8 + eg] = acc[q][0];
        else          Bbuf[b16 + eg - RNK] = acc[q][0];
        int e1 = eg + 16;
        if (e1 < RNK + NST) Bbuf[b16 + e1 - RNK] = acc[q][1];
        else                Cbuf[b16 + e1 - RNK - NST] = acc[q][1];
        if (has3) Cbuf[b16 + eg + 32 - RNK - NST] = acc[q][2];
    }
}

// -------- kernel 4a: chunk-local scan -> per-chunk summary (P, h_end) --------
// Summary stored interleaved float2 {P, h}: one coalesced 8B store here,
// one 8B load per fold iteration in k_scanC.
__global__ __launch_bounds__(256) void k_scanA(
        const float* __restrict__ xi, const float* __restrict__ drbuf,
        const float* __restrict__ Bbuf, const float* __restrict__ A_logs,
        const float* __restrict__ W_dt, const float* __restrict__ b_dt,
        float2* __restrict__ sum2) {
    __shared__ float2 sDU2[16][STDU];   // [ch][s] {delta, delta*u}
    __shared__ float  sB1t[16][STB1];   // [n][s]
    int c   = blockIdx.x;
    int blk = blockIdx.y;
    int k   = blk / (BATCH * CGRP);
    int rem = blk % (BATCH * CGRP);
    int b   = rem / CGRP;
    int cg  = rem % CGRP;
    int d0  = cg * 16;
    int t    = threadIdx.x;
    int lane = t & 63, wave = t >> 6;
    int grp  = lane >> 4, n = lane & 15;
    int ch   = wave * 4 + grp;
    int d    = d0 + ch;
    float A = -__expf(A_logs[((size_t)(k * DIN + d)) * NST + n]);
    size_t kb = (size_t)(k * BATCH + b);
    const float* drp = drbuf + kb * LL * 8;
    const float* bp  = Bbuf  + kb * LL * NST;
    const float* up  = xi    + (size_t)b * LL * DIN;
    // staging identity
    int ss  = t >> 2;            // 0..63
    int cc0 = (t & 3) * 4;       // 0,4,8,12
    float4 wr[RNK];
#pragma unroll
    for (int r = 0; r < RNK; r++)
        wr[r] = *(const float4*)(W_dt + ((size_t)k * RNK + r) * DIN + d0 + cc0);
    float4 bb4 = *(const float4*)(b_dt + k * DIN + d0 + cc0);
    int l0 = c * SCH;
    {
        int l  = l0 + ss;
        int lr = seq_to_lr(k, l);
        float4 r03 = *(const float4*)(drp + (size_t)l * 8);
        float2 r45 = *(const float2*)(drp + (size_t)l * 8 + 4);
        float4 dlt = delta4(r03, r45, wr, bb4);
        float4 u4  = *(const float4*)(up + (size_t)lr * DIN + d0 + cc0);
        float4 B4  = *(const float4*)(bp + (size_t)l * NST + cc0);
        sDU2[cc0 + 0][ss] = make_float2(dlt.x, dlt.x * u4.x);
        sDU2[cc0 + 1][ss] = make_float2(dlt.y, dlt.y * u4.y);
        sDU2[cc0 + 2][ss] = make_float2(dlt.z, dlt.z * u4.z);
        sDU2[cc0 + 3][ss] = make_float2(dlt.w, dlt.w * u4.w);
        sB1t[cc0 + 0][ss] = B4.x;
        sB1t[cc0 + 1][ss] = B4.y;
        sB1t[cc0 + 2][ss] = B4.z;
        sB1t[cc0 + 3][ss] = B4.w;
    }
    __syncthreads();
    float h = 0.0f, P = 1.0f;
#pragma unroll 2
    for (int s4 = 0; s4 < SCH; s4 += 4) {
        float4 duA = *(const float4*)&sDU2[ch][s4];
        float4 duB = *(const float4*)&sDU2[ch][s4 + 2];
        float4 bq  = *(const float4*)&sB1t[n][s4];
        float dA;
        dA = __expf(duA.x * A); h = fmaf(dA, h, duA.y * bq.x); P *= dA;
        dA = __expf(duA.z * A); h = fmaf(dA, h, duA.w * bq.y); P *= dA;
        dA = __expf(duB.x * A); h = fmaf(dA, h, duB.y * bq.z); P *= dA;
        dA = __expf(duB.z * A); h = fmaf(dA, h, duB.w * bq.w); P *= dA;
    }
    sum2[hs_idx(c, (int)kb, d, n)] = make_float2(P, h);
}

// -------- kernel 4b: chunk-local scan with inline prefix fold; emit y --------
// Fold is unrolled x8: 8 independent float2 loads per batch (one waitcnt),
// then 8 serial FMAs — cuts the per-block fold latency ~6x vs the serial
// load-load-fma chain. Fold order (ascending j) unchanged -> bit-identical.
__global__ __launch_bounds__(256) void k_scanC(
        const float* __restrict__ xi, const float* __restrict__ drbuf,
        const float* __restrict__ Bbuf, const float* __restrict__ Cbuf,
        const float* __restrict__ A_logs, const float* __restrict__ W_dt,
        const float* __restrict__ b_dt,
        const float2* __restrict__ sum2,
        float* __restrict__ ydir) {
    __shared__ float2 sDU2[16][STDU];   // [ch][s] {delta, delta*u}
    __shared__ float2 sBC2[16][STBC];   // [n][s]  {B, C}
    __shared__ float  sY[16][STY];      // [ch][s]
    int c   = blockIdx.x;
    int blk = blockIdx.y;
    int k   = blk / (BATCH * CGRP);
    int rem = blk % (BATCH * CGRP);
    int b   = rem / CGRP;
    int cg  = rem % CGRP;
    int d0  = cg * 16;
    int t    = threadIdx.x;
    int lane = t & 63, wave = t >> 6;
    int grp  = lane >> 4, n = lane & 15;
    int ch   = wave * 4 + grp;
    int d    = d0 + ch;
    float A = -__expf(A_logs[((size_t)(k * DIN + d)) * NST + n]);
    size_t kb = (size_t)(k * BATCH + b);
    const float* drp = drbuf + kb * LL * 8;
    const float* bp  = Bbuf  + kb * LL * NST;
    const float* cp  = Cbuf  + kb * LL * NST;
    const float* up  = xi    + (size_t)b * LL * DIN;
    float*       yp  = ydir  + kb * LL * DIN;     // per-direction slice
    // ---- inline prefix fold: h_in for this (d, n) over chunks 0..c-1 ----
    float hin = 0.0f;
    {
        int j = 0;
        for (; j + 8 <= c; j += 8) {
            float2 a0 = sum2[hs_idx(j + 0, (int)kb, d, n)];
            float2 a1 = sum2[hs_idx(j + 1, (int)kb, d, n)];
            float2 a2 = sum2[hs_idx(j + 2, (int)kb, d, n)];
            float2 a3 = sum2[hs_idx(j + 3, (int)kb, d, n)];
            float2 a4 = sum2[hs_idx(j + 4, (int)kb, d, n)];
            float2 a5 = sum2[hs_idx(j + 5, (int)kb, d, n)];
            float2 a6 = sum2[hs_idx(j + 6, (int)kb, d, n)];
            float2 a7 = sum2[hs_idx(j + 7, (int)kb, d, n)];
            hin = fmaf(a0.x, hin, a0.y);
            hin = fmaf(a1.x, hin, a1.y);
            hin = fmaf(a2.x, hin, a2.y);
            hin = fmaf(a3.x, hin, a3.y);
            hin = fmaf(a4.x, hin, a4.y);
            hin = fmaf(a5.x, hin, a5.y);
            hin = fmaf(a6.x, hin, a6.y);
            hin = fmaf(a7.x, hin, a7.y);
        }
        for (; j < c; j++) {
            float2 a = sum2[hs_idx(j, (int)kb, d, n)];
            hin = fmaf(a.x, hin, a.y);
        }
    }
    // ---- stage chunk data ----
    int ss  = t >> 2;
    int cc0 = (t & 3) * 4;
    float4 wr[RNK];
#pragma unroll
    for (int r = 0; r < RNK; r++)
        wr[r] = *(const float4*)(W_dt + ((size_t)k * RNK + r) * DIN + d0 + cc0);
    float4 bb4 = *(const float4*)(b_dt + k * DIN + d0 + cc0);
    int l0 = c * SCH;
    {
        int l  = l0 + ss;
        int lr = seq_to_lr(k, l);
        float4 r03 = *(const float4*)(drp + (size_t)l * 8);
        float2 r45 = *(const float2*)(drp + (size_t)l * 8 + 4);
        float4 dlt = delta4(r03, r45, wr, bb4);
        float4 u4  = *(const float4*)(up + (size_t)lr * DIN + d0 + cc0);
        float4 B4  = *(const float4*)(bp + (size_t)l * NST + cc0);
        float4 C4  = *(const float4*)(cp + (size_t)l * NST + cc0);
        sDU2[cc0 + 0][ss] = make_float2(dlt.x, dlt.x * u4.x);
        sDU2[cc0 + 1][ss] = make_float2(dlt.y, dlt.y * u4.y);
        sDU2[cc0 + 2][ss] = make_float2(dlt.z, dlt.z * u4.z);
        sDU2[cc0 + 3][ss] = make_float2(dlt.w, dlt.w * u4.w);
        sBC2[cc0 + 0][ss] = make_float2(B4.x, C4.x);
        sBC2[cc0 + 1][ss] = make_float2(B4.y, C4.y);
        sBC2[cc0 + 2][ss] = make_float2(B4.z, C4.z);
        sBC2[cc0 + 3][ss] = make_float2(B4.w, C4.w);
    }
    __syncthreads();
    float h = hin;
#pragma unroll 2
    for (int s4 = 0; s4 < SCH; s4 += 4) {
        float4 duA = *(const float4*)&sDU2[ch][s4];
        float4 duB = *(const float4*)&sDU2[ch][s4 + 2];
        float4 bcA = *(const float4*)&sBC2[n][s4];
        float4 bcB = *(const float4*)&sBC2[n][s4 + 2];
        float dA, y0, y1, y2, y3;
        dA = __expf(duA.x * A); h = fmaf(dA, h, duA.y * bcA.x); y0 = row_reduce16(h * bcA.y);
        dA = __expf(duA.z * A); h = fmaf(dA, h, duA.w * bcA.z); y1 = row_reduce16(h * bcA.w);
        dA = __expf(duB.x * A); h = fmaf(dA, h, duB.y * bcB.x); y2 = row_reduce16(h * bcB.y);
        dA = __expf(duB.z * A); h = fmaf(dA, h, duB.w * bcB.z); y3 = row_reduce16(h * bcB.w);
        if (n == 0) *(float4*)&sY[ch][s4] = make_float4(y0, y1, y2, y3);
    }
    __syncthreads();
    // vectorized writeback: one float4 store per thread (s = t>>2, quad = t&3)
    {
        int s  = t >> 2;
        int c4 = (t & 3) * 4;
        int lr = seq_to_lr(k, l0 + s);
        float4 v = make_float4(sY[c4 + 0][s], sY[c4 + 1][s],
                               sY[c4 + 2][s], sY[c4 + 3][s]);
        *(float4*)&yp[(size_t)lr * DIN + d0 + c4] = v;
    }
}

// ------- kernel 5: gather 4 directions + D*u + gate + out-projection ---------
constexpr int K5_PIX = 8;
__global__ __launch_bounds__(192) void k_out(
        const float* __restrict__ ydir, const float* __restrict__ xi,
        const float* __restrict__ zbuf, const float* __restrict__ Ds,
        const float* __restrict__ W_out, float* __restrict__ out) {
    __shared__ float g[DIN][12];           // [dd][p] padded
    __shared__ float so[CDIM][9];          // padded stores
    int gp0 = blockIdx.x * K5_PIX;
    int b   = gp0 / LL;
    int l0  = gp0 - b * LL;
    int t   = threadIdx.x;
    for (int i = t; i < K5_PIX * DIN; i += 192) {
        int p = i / DIN, dd = i % DIN;
        size_t off = (size_t)(gp0 + p) * DIN + dd;
        float y = ydir[off] + ydir[SZ_PX + off]
                + ydir[2 * SZ_PX + off] + ydir[3 * SZ_PX + off];
        float dsum = Ds[dd] + Ds[DIN + dd] + Ds[2 * DIN + dd] + Ds[3 * DIN + dd];
        y = fmaf(xi[off], dsum, y);
        g[dd][p] = y * silu(zbuf[off]);
    }
    __syncthreads();
    int f    = t % CDIM;
    int half = t / CDIM;
    float acc[4] = {0.f, 0.f, 0.f, 0.f};
#pragma unroll 4
    for (int dd = 0; dd < DIN; dd++) {
        float wv = W_out[dd * CDIM + f];
        float4 gv = *(const float4*)&g[dd][half * 4];
        acc[0] = fmaf(gv.x, wv, acc[0]);
        acc[1] = fmaf(gv.y, wv, acc[1]);
        acc[2] = fmaf(gv.z, wv, acc[2]);
        acc[3] = fmaf(gv.w, wv, acc[3]);
    }
#pragma unroll
    for (int p = 0; p < 4; p++) so[f][half * 4 + p] = acc[p];
    __syncthreads();
    for (int i = t; i < CDIM * K5_PIX; i += 192) {
        int f2 = i / K5_PIX, p2 = i % K5_PIX;
        out[((size_t)(b * CDIM + f2)) * LL + l0 + p2] = so[f2][p2];
    }
}

// ---------------- launch ----------------------------------------------------
extern "C" void kernel_launch(void* const* d_in, const int* in_sizes, int n_in,
                              void* d_out, int out_size, void* d_ws, size_t ws_size,
                              hipStream_t stream) {
    const float* x       = (const float*)d_in[0];
    const float* W_in    = (const float*)d_in[1];
    const float* W_conv  = (const float*)d_in[2];
    const float* b_conv  = (const float*)d_in[3];
    const float* W_xproj = (const float*)d_in[4];
    const float* W_dt    = (const float*)d_in[5];
    const float* b_dt    = (const float*)d_in[6];
    const float* A_logs  = (const float*)d_in[7];
    const float* Ds      = (const float*)d_in[8];
    const float* W_out   = (const float*)d_in[9];
    float* out = (float*)d_out;
    float* ws  = (float*)d_ws;

    float* xp    = ws + OFF_XP;
    float* z     = ws + OFF_Z;
    float* xi    = ws + OFF_XI;
    float* drbuf = ws + OFF_DR;
    float* Bbuf  = ws + OFF_B;
    float* Cbuf  = ws + OFF_C;
    float* ydir  = ws + OFF_YD;
    float2* sum2 = (float2*)(ws + OFF_HE);
    float* Wt    = ws + OFF_WT;

    k_inproj<<<(BATCH * LL) / K1_PIX, 384, 0, stream>>>(x, W_in, W_xproj, xp, z, Wt);
    k_conv<<<(BATCH * LL) / KC_PIX, 192, 0, stream>>>(xp, W_conv, b_conv, xi);
    dim3 g3((BATCH * LL) / K3_PIX, NK);
    k_xproj<<<g3, 256, 0, stream>>>(xi, Wt, drbuf, Bbuf, Cbuf);
    dim3 gs(NCH, NK * BATCH * CGRP);
    k_scanA<<<gs, 256, 0, stream>>>(xi, drbuf, Bbuf, A_logs, W_dt, b_dt, sum2);
    k_scanC<<<gs, 256, 0, stream>>>(xi, drbuf, Bbuf, Cbuf, A_logs, W_dt, b_dt, sum2, ydir);
    k_out<<<(BATCH * LL) / K5_PIX, 192, 0, stream>>>(ydir, xi, z, Ds, W_out, out);
}